// Round 8
// baseline (247.440 us; speedup 1.0000x reference)
//
#include <hip/hip_runtime.h>

#define BB 32
#define TT 512
#define DD 768
#define NTHREADS 192            // = DD/4 float4 lanes per row
#define TOK_PER_BLOCK 8         // source tokens per block
#define BLOCKS_PER_BATCH (TT / TOK_PER_BLOCK)   // 64

typedef float f4 __attribute__((ext_vector_type(4)));

// Round 8: round-7 kernel + ONE change — nontemporal stores -> plain stores.
// Evidence chain: round-6 probe: kernel = 43.8 us; round-7 load-hoist:
// -6.7 us -> kernel ~37 us. Round-5 probe: a PLAIN-store 210 MB sweep costs
// +2.4 us (L3-absorbed: end-of-kernel release fence only needs dirty lines
// in the die-level L3; writeback to HBM is lazy, off the critical path).
// NT stores bypass that absorption (no-allocate hint) and must drain to HBM
// synchronously: 210 MB / 6.45 TB/s = 32.5 us — which plus ~4 us of
// scan/read matches the 37 us kernel exactly. The round-2/3 NT-vs-plain A/B
// showed nothing because that structure (run-walk) was latency-bound at
// ~49 us by its own dynamic-count vmcnt drains, masking the store term.
// NT ("don't pollute cache") is an anti-optimization when out is L3-sized.
__global__ __launch_bounds__(NTHREADS) void lr_fused_kernel(
    const float* __restrict__ x, const float* __restrict__ dur,
    float* __restrict__ out, int t_out) {
    __shared__ int scum[TT];
    const int b = blockIdx.y;
    const int tid = threadIdx.x;
    const int s0 = blockIdx.x * TOK_PER_BLOCK;

    const f4* xb = (const f4*)(x + (size_t)b * TT * DD);

    // Issue all 8 row loads NOW; latency hides under the scan below.
    f4 v[TOK_PER_BLOCK];
    #pragma unroll
    for (int k = 0; k < TOK_PER_BLOCK; ++k)
        v[k] = xb[(size_t)(s0 + k) * NTHREADS + tid];

    // reps into LDS
    for (int i = tid; i < TT; i += NTHREADS) {
        float d = fmaxf(dur[b * TT + i], 0.0f);
        scum[i] = (int)floorf(d + 0.5f);
    }
    __syncthreads();

    // Hillis-Steele inclusive scan over 512 elements with 192 threads.
    #pragma unroll
    for (int off = 1; off < TT; off <<= 1) {
        const int i0 = tid, i1 = tid + NTHREADS, i2 = tid + 2 * NTHREADS;
        int v0 = (i0 >= off) ? scum[i0 - off] : 0;
        int v1 = (i1 >= off) ? scum[i1 - off] : 0;
        int v2 = (i2 < TT && i2 >= off) ? scum[i2 - off] : 0;
        __syncthreads();
        scum[i0] += v0;
        scum[i1] += v1;
        if (i2 < TT) scum[i2] += v2;
        __syncthreads();
    }

    // Scatter this block's 8 source tokens from registers.
    f4* ob = (f4*)(out + (size_t)b * (size_t)t_out * DD);

    #pragma unroll
    for (int k = 0; k < TOK_PER_BLOCK; ++k) {
        const int t = s0 + k;
        const int start = (t == 0) ? 0 : scum[t - 1];
        const int end = scum[t];
        for (int p = start; p < end; ++p)      // 0..8 iters, block-uniform
            ob[(size_t)p * NTHREADS + tid] = v[k];
    }

    // Tail zero: rows [total, t_out) striped across the batch's 64 blocks.
    const int total = scum[TT - 1];
    const f4 z = (f4)(0.0f);
    for (int pos = total + blockIdx.x; pos < t_out; pos += BLOCKS_PER_BATCH)
        ob[(size_t)pos * NTHREADS + tid] = z;
}

extern "C" void kernel_launch(void* const* d_in, const int* in_sizes, int n_in,
                              void* d_out, int out_size, void* d_ws, size_t ws_size,
                              hipStream_t stream) {
    const float* x   = (const float*)d_in[0];
    const float* dur = (const float*)d_in[1];
    float* out = (float*)d_out;
    (void)d_ws; (void)ws_size; (void)in_sizes; (void)n_in;

    const int t_out = out_size / (BB * DD);

    dim3 grid(BLOCKS_PER_BATCH, BB);           // 64 x 32 blocks
    lr_fused_kernel<<<grid, NTHREADS, 0, stream>>>(x, dur, out, t_out);
}